// Round 8
// baseline (106.182 us; speedup 1.0000x reference)
//
#include <hip/hip_runtime.h>

#define Kc 512
#define Dc 64
#define Hc 64
#define Bc 16
#define Tc 16384
#define Nt (Bc * Tc)              // 262144 tokens
#define LN_EPS 1e-5f
// loss = (1 + 0.25) * mean over N*D elements
#define LOSS_SCALE (1.25f / 16777216.0f)   // 1.25 / (Nt*Dc)

#define GATHER_BLOCKS 4096
#define GATHER_THREADS 256
#define GATHER_ITERS 4            // 4096*256*4 = 4,194,304 float4s = Nt*16

typedef float v4f __attribute__((ext_vector_type(4)));  // native vec for NT store

// ---------------------------------------------------------------------------
// Kernel 1: per-t-value table precompute (R7 coalesced version — WIN, keep).
// 512 blocks x 256 threads. Block v: encoder (first wave) -> z[64] ->
// coalesced 4-wave argmin (wave reads 64 consecutive float4s = 4 whole rows
// per iter; 16-lane-group shfl reduce).
// ---------------------------------------------------------------------------
__global__ __launch_bounds__(256) void precompute_kernel(
    const float* __restrict__ W1, const float* __restrict__ b1,
    const float* __restrict__ ln_g, const float* __restrict__ ln_b,
    const float* __restrict__ W2, const float* __restrict__ b2,
    const float* __restrict__ cb,
    float* __restrict__ q_table, float* __restrict__ idxf_table,
    float* __restrict__ d2_table)
{
    const int v   = blockIdx.x;      // t value, 0..511
    const int tid = threadIdx.x;     // 0..255
    const int lane = tid & 63;
    const int wave = tid >> 6;       // 0..3

    __shared__ float s_h[Hc];
    __shared__ __align__(16) float s_z[Dc];
    __shared__ float s_bd[4];
    __shared__ int   s_bk[4];
    __shared__ int   s_win;
    __shared__ float s_wd;

    // ---- encoder on the first wave only (lane = H index = D index) ----
    if (tid < 64) {
        const float norm_t = (float)v * (2.0f / (float)(Kc - 1)) - 1.0f;
        float h = norm_t * W1[lane] + b1[lane];

        float s = h;
        #pragma unroll
        for (int o = 32; o > 0; o >>= 1) s += __shfl_xor(s, o);
        const float mu = s * (1.0f / (float)Hc);
        const float d = h - mu;
        float vs = d * d;
        #pragma unroll
        for (int o = 32; o > 0; o >>= 1) vs += __shfl_xor(vs, o);
        const float var = vs * (1.0f / (float)Hc);
        float hn = d * rsqrtf(var + LN_EPS) * ln_g[lane] + ln_b[lane];
        hn = fmaxf(hn, 0.0f);
        s_h[lane] = hn;
        __builtin_amdgcn_s_waitcnt(0);   // LDS write visible within wave
        // z[lane] = sum_h s_h[h] * W2[h][lane] + b2[lane]
        float z = b2[lane];
        #pragma unroll
        for (int hh = 0; hh < Hc; ++hh) z = fmaf(s_h[hh], W2[hh * Dc + lane], z);
        s_z[lane] = z;
    }
    __syncthreads();

    // ---- coalesced argmin ----
    const float4* cb4 = (const float4*)cb;
    const float4 zz = ((const float4*)s_z)[lane & 15];   // loop-invariant
    const int rowgrp = lane >> 4;                        // 0..3

    float best_d = 3.4e38f;
    int best_k = 0;
    const int base = wave * 2048;
    #pragma unroll 4
    for (int i = 0; i < 32; ++i) {
        const float4 e = cb4[base + i * 64 + lane];
        float d0 = zz.x - e.x, d1 = zz.y - e.y, d2 = zz.z - e.z, d3 = zz.w - e.w;
        float pd = d0 * d0;
        pd = fmaf(d1, d1, pd); pd = fmaf(d2, d2, pd); pd = fmaf(d3, d3, pd);
        pd += __shfl_xor(pd, 1);
        pd += __shfl_xor(pd, 2);
        pd += __shfl_xor(pd, 4);
        pd += __shfl_xor(pd, 8);
        const int k = wave * 128 + i * 4 + rowgrp;
        if (pd < best_d) { best_d = pd; best_k = k; }  // k ascends per lane
    }
    #pragma unroll
    for (int o = 32; o > 0; o >>= 1) {
        const float od = __shfl_xor(best_d, o);
        const int   ok = __shfl_xor(best_k, o);
        if (od < best_d || (od == best_d && ok < best_k)) { best_d = od; best_k = ok; }
    }
    if (lane == 0) { s_bd[wave] = best_d; s_bk[wave] = best_k; }
    __syncthreads();
    if (tid == 0) {
        float bd = s_bd[0]; int bk = s_bk[0];
        #pragma unroll
        for (int w = 1; w < 4; ++w) {
            const float od = s_bd[w]; const int ok = s_bk[w];
            if (od < bd || (od == bd && ok < bk)) { bd = od; bk = ok; }
        }
        s_win = bk; s_wd = bd;
    }
    __syncthreads();

    if (tid < 64) q_table[v * Dc + tid] = cb[s_win * Dc + tid];
    if (tid == 0) { idxf_table[v] = (float)s_win; d2_table[v] = s_wd; }
}

// ---------------------------------------------------------------------------
// Kernel 2: gather. R6 structure (4096 blocks, batched ILP, plain partial
// store). ONE change vs R7: nontemporal out_q stores — plain stores
// write-allocate 64MB through the 32MB aggregate L2 (thrash); the harness
// fill kernel sustains 6 TB/s with NT. R4's NT test was confounded by a 4x
// block cut; this isolates the store path at full occupancy.
// ---------------------------------------------------------------------------
__global__ __launch_bounds__(GATHER_THREADS) void gather_kernel(
    const int* __restrict__ t, const float* __restrict__ q_table,
    const float* __restrict__ idxf_table, const float* __restrict__ d2_table,
    float* __restrict__ out_q, float* __restrict__ out_idx,
    float* __restrict__ partials)
{
    const int tid = threadIdx.x;
    const int g0  = blockIdx.x * GATHER_THREADS + tid;
    const int stride = GATHER_BLOCKS * GATHER_THREADS;   // 2^20, %16==0
    const int part  = g0 & 15;                           // same for all iters

    // phase 1: all t loads in flight
    int tvs[GATHER_ITERS];
    #pragma unroll
    for (int i = 0; i < GATHER_ITERS; ++i)
        tvs[i] = t[(g0 + i * stride) >> 4];

    // phase 2: all table reads in flight (L2-resident, 128KB table)
    float4 qs[GATHER_ITERS];
    #pragma unroll
    for (int i = 0; i < GATHER_ITERS; ++i)
        qs[i] = ((const float4*)q_table)[(tvs[i] << 4) + part];

    // phase 3: nontemporal streaming stores (bypass L2 write-allocate)
    #pragma unroll
    for (int i = 0; i < GATHER_ITERS; ++i) {
        const v4f qv = { qs[i].x, qs[i].y, qs[i].z, qs[i].w };
        __builtin_nontemporal_store(qv, &((v4f*)out_q)[g0 + i * stride]);
    }

    // idx + loss contributions (part==0 lanes only; 4 lanes/wave)
    float lsum = 0.0f;
    if (part == 0) {
        #pragma unroll
        for (int i = 0; i < GATHER_ITERS; ++i) {
            const int token = (g0 + i * stride) >> 4;
            out_idx[token] = idxf_table[tvs[i]];
            lsum += d2_table[tvs[i]];
        }
    }

    // block reduction -> one partial per block (plain store; kernel boundary
    // provides cross-XCD visibility for the reduce kernel)
    #pragma unroll
    for (int o = 32; o > 0; o >>= 1) lsum += __shfl_xor(lsum, o);
    __shared__ float s_partial[4];
    if ((tid & 63) == 0) s_partial[tid >> 6] = lsum;
    __syncthreads();
    if (tid == 0)
        partials[blockIdx.x] =
            s_partial[0] + s_partial[1] + s_partial[2] + s_partial[3];
}

// ---------------------------------------------------------------------------
// Kernel 3: reduce 4096 partials -> loss. Single block, deterministic.
// ---------------------------------------------------------------------------
__global__ __launch_bounds__(256) void loss_reduce_kernel(
    const float* __restrict__ partials, float* __restrict__ out_loss)
{
    const int tid = threadIdx.x;
    float s = 0.0f;
    #pragma unroll
    for (int i = 0; i < GATHER_BLOCKS / 256; ++i)
        s += partials[i * 256 + tid];
    #pragma unroll
    for (int o = 32; o > 0; o >>= 1) s += __shfl_xor(s, o);
    __shared__ float s_partial[4];
    if ((tid & 63) == 0) s_partial[tid >> 6] = s;
    __syncthreads();
    if (tid == 0)
        out_loss[0] = (s_partial[0] + s_partial[1] + s_partial[2] + s_partial[3])
                      * LOSS_SCALE;
}

extern "C" void kernel_launch(void* const* d_in, const int* in_sizes, int n_in,
                              void* d_out, int out_size, void* d_ws, size_t ws_size,
                              hipStream_t stream) {
    const int*   t        = (const int*)d_in[0];     // [B,T,1] int32
    const float* W1       = (const float*)d_in[1];   // [1,H]
    const float* b1       = (const float*)d_in[2];   // [H]
    const float* ln_g     = (const float*)d_in[3];   // [H]
    const float* ln_b     = (const float*)d_in[4];   // [H]
    const float* W2       = (const float*)d_in[5];   // [H,D]
    const float* b2       = (const float*)d_in[6];   // [D]
    const float* codebook = (const float*)d_in[7];   // [K,D]

    float* out      = (float*)d_out;
    float* out_q    = out;                     // Nt*Dc floats
    float* out_idx  = out + (size_t)Nt * Dc;   // Nt floats (idx as float)
    float* out_loss = out_idx + Nt;            // 1 float

    float* ws        = (float*)d_ws;
    float* q_table   = ws;                        // 512*64
    float* idxf_tab  = ws + Kc * Dc;              // 512
    float* d2_tab    = idxf_tab + Kc;             // 512
    float* partials  = d2_tab + Kc;               // 4096

    precompute_kernel<<<Kc, 256, 0, stream>>>(
        W1, b1, ln_g, ln_b, W2, b2, codebook,
        q_table, idxf_tab, d2_tab);

    gather_kernel<<<GATHER_BLOCKS, GATHER_THREADS, 0, stream>>>(
        t, q_table, idxf_tab, d2_tab, out_q, out_idx, partials);

    loss_reduce_kernel<<<1, 256, 0, stream>>>(partials, out_loss);
}